// Round 9
// baseline (51.225 us; speedup 1.0000x reference)
//
#include <hip/hip_runtime.h>
#include <hip/hip_fp16.h>
#include <stdint.h>

#define BINS    64
#define NSLOT   19            // uint2 slots per column (38 dwords: bins -4..71 packed)
#define THREADS 128
#define CHUNKS  128           // blocks per channel (each block does pred AND target)
#define NPIX    (512*512)
#define PPB     (NPIX / CHUNKS)        // 2048 px per image per block
#define ITERS   (PPB / 4 / THREADS)    // 4 float4 iterations per image
#define NCH     12

__device__ __forceinline__ uint32_t h2add(uint32_t u, __half2 w) {
    __half2 v = *(__half2*)&u;
    v = __hadd2(v, w);
    return *(uint32_t*)&v;
}

__device__ __forceinline__ void gatomic_fadd(float* p, float v) {
    asm volatile("global_atomic_add_f32 %0, %1, off" :: "v"(p), "v"(v) : "memory");
}

__global__ __launch_bounds__(THREADS) void hist_kernel(
    const float* __restrict__ pred, const float* __restrict__ target,
    float* __restrict__ chist /* [2][NCH][BINS] */)
{
    __shared__ __align__(16) uint2 lh[2 * THREADS * NSLOT];   // 38912 B
    const int tid = threadIdx.x;
    uint2* colP = &lh[tid * NSLOT];
    uint2* colT = &lh[(THREADS + tid) * NSLOT];
    #pragma unroll
    for (int i = 0; i < NSLOT; ++i) {
        colP[i] = make_uint2(0u, 0u);
        colT[i] = make_uint2(0u, 0u);
    }
    __syncthreads();

    const int chunk = blockIdx.x;
    const int ch    = blockIdx.y;
    const float4* srcP = (const float4*)(pred   + (size_t)ch * NPIX + (size_t)chunk * PPB);
    const float4* srcT = (const float4*)(target + (size_t)ch * NPIX + (size_t)chunk * PPB);

    // C_k = exp(-k*k/2)
    const float C1 = 0.60653065971e0f;
    const float C2 = 0.13533528324e0f;
    const float C3 = 1.11089965382e-2f;
    const float C4 = 3.35462627903e-4f;
    const float C5 = 3.72665317208e-6f;
    const float C6 = 1.52299797447e-8f;

    float4 vP = srcP[tid], vT = srcT[tid];
    #pragma unroll
    for (int k = 0; k < ITERS; ++k) {
        float4 vPn = (k + 1 < ITERS) ? srcP[(size_t)(k + 1) * THREADS + tid]
                                     : make_float4(0.f, 0.f, 0.f, 0.f);
        float4 vTn = (k + 1 < ITERS) ? srcT[(size_t)(k + 1) * THREADS + tid]
                                     : make_float4(0.f, 0.f, 0.f, 0.f);
        float xpv[4] = {vP.x, vP.y, vP.z, vP.w};
        float xtv[4] = {vT.x, vT.y, vT.z, vT.w};
        #pragma unroll
        for (int e = 0; e < 4; ++e) {
            // --- addresses first (cheap), reads issued early ---
            float xsP = xpv[e] * 64.0f;
            float fqP = floorf(xsP * 0.25f);
            int   QP  = (int)fqP;
            float dP  = xsP - 4.0f * fqP - 1.5f;    // [-1.5, 2.5)
            float xsT = xtv[e] * 64.0f;
            float fqT = floorf(xsT * 0.25f);
            int   QT  = (int)fqT;
            float dT  = xsT - 4.0f * fqT - 1.5f;
            uint2* cP = colP + QP;
            uint2* cT = colT + QT;
            uint2 pa0 = cP[0], pa1 = cP[1], pa2 = cP[2];
            uint2 ta0 = cT[0], ta1 = cT[1], ta2 = cT[2];

            // --- exp-heavy weight computation overlaps LDS latency ---
            float tP0 = __expf(-0.5f * dP * dP);
            float gP  = __expf(dP);
            float giP = __expf(-dP);
            float tP1 = tP0*C1, tP2 = tP0*C2, tP3 = tP0*C3;
            float tP4 = tP0*C4, tP5 = tP0*C5, tP6 = tP0*C6;
            float gP2 = gP*gP,   gP3 = gP2*gP,  gP4 = gP2*gP2;
            float gP5 = gP3*gP2, gP6 = gP3*gP3;
            float hP2 = giP*giP, hP3 = hP2*giP, hP4 = hP2*hP2, hP5 = hP3*hP2;
            __half2 wp0 = __floats2half2_rn(tP5*hP5, tP4*hP4);
            __half2 wp1 = __floats2half2_rn(tP3*hP3, tP2*hP2);
            __half2 wp2 = __floats2half2_rn(tP1*giP, tP0);
            __half2 wp3 = __floats2half2_rn(tP1*gP,  tP2*gP2);
            __half2 wp4 = __floats2half2_rn(tP3*gP3, tP4*gP4);
            __half2 wp5 = __floats2half2_rn(tP5*gP5, tP6*gP6);

            float tT0 = __expf(-0.5f * dT * dT);
            float gT  = __expf(dT);
            float giT = __expf(-dT);
            float tT1 = tT0*C1, tT2 = tT0*C2, tT3 = tT0*C3;
            float tT4 = tT0*C4, tT5 = tT0*C5, tT6 = tT0*C6;
            float gT2 = gT*gT,   gT3 = gT2*gT,  gT4 = gT2*gT2;
            float gT5 = gT3*gT2, gT6 = gT3*gT3;
            float hT2 = giT*giT, hT3 = hT2*giT, hT4 = hT2*hT2, hT5 = hT3*hT2;
            __half2 wt0 = __floats2half2_rn(tT5*hT5, tT4*hT4);
            __half2 wt1 = __floats2half2_rn(tT3*hT3, tT2*hT2);
            __half2 wt2 = __floats2half2_rn(tT1*giT, tT0);
            __half2 wt3 = __floats2half2_rn(tT1*gT,  tT2*gT2);
            __half2 wt4 = __floats2half2_rn(tT3*gT3, tT4*gT4);
            __half2 wt5 = __floats2half2_rn(tT5*gT5, tT6*gT6);

            // --- merge + write back ---
            pa0.x = h2add(pa0.x, wp0); pa0.y = h2add(pa0.y, wp1);
            pa1.x = h2add(pa1.x, wp2); pa1.y = h2add(pa1.y, wp3);
            pa2.x = h2add(pa2.x, wp4); pa2.y = h2add(pa2.y, wp5);
            ta0.x = h2add(ta0.x, wt0); ta0.y = h2add(ta0.y, wt1);
            ta1.x = h2add(ta1.x, wt2); ta1.y = h2add(ta1.y, wt3);
            ta2.x = h2add(ta2.x, wt4); ta2.y = h2add(ta2.y, wt5);
            cP[0] = pa0; cP[1] = pa1; cP[2] = pa2;
            cT[0] = ta0; cT[1] = ta1; cT[2] = ta2;
        }
        vP = vPn; vT = vTn;
    }
    __syncthreads();

    // fold columns into f32 registers: 6 groups (3 pred, 3 target) x 19 slots
    const int g = tid / NSLOT;        // 0..6
    const int j = tid - g * NSLOT;
    float s0 = 0.f, s1 = 0.f, s2 = 0.f, s3 = 0.f;
    if (g < 6) {
        const int img = (g < 3) ? 0 : 1;
        const int gg  = (g < 3) ? g : g - 3;
        const uint2* base = lh + img * THREADS * NSLOT;
        for (int c = gg; c < THREADS; c += 3) {
            uint2 u = base[c * NSLOT + j];
            __half2 h0 = *(__half2*)&u.x, h1 = *(__half2*)&u.y;
            s0 += __low2float(h0); s1 += __high2float(h0);
            s2 += __low2float(h1); s3 += __high2float(h1);
        }
    }
    __syncthreads();                   // all fold reads done
    float4* scratch = (float4*)lh;     // 114 float4 = 456 dwords, overwrites cols 0..
    if (g < 6) scratch[g * NSLOT + j] = make_float4(s0, s1, s2, s3);
    __syncthreads();

    if (tid < 2 * NSLOT) {
        const int img = tid / NSLOT;          // 0=pred, 1=target
        const int jj  = tid - img * NSLOT;
        const int gb  = img * 3;
        float4 a = scratch[(gb + 0) * NSLOT + jj];
        float4 b = scratch[(gb + 1) * NSLOT + jj];
        float4 c = scratch[(gb + 2) * NSLOT + jj];
        // slot jj covers bins 4*jj-4 .. 4*jj-1
        int b0 = 4 * jj - 4;
        if (b0 >= 0 && b0 + 3 < BINS + 1) {   // jj in 1..16 -> bins 0..63
            float* gp = chist + ((size_t)img * NCH + ch) * BINS + b0;
            gatomic_fadd(gp + 0, a.x + b.x + c.x);
            gatomic_fadd(gp + 1, a.y + b.y + c.y);
            gatomic_fadd(gp + 2, a.z + b.z + c.z);
            gatomic_fadd(gp + 3, a.w + b.w + c.w);
        }
    }
    asm volatile("s_waitcnt vmcnt(0)" ::: "memory");
}

__global__ __launch_bounds__(256) void finalize_kernel(
    const float* __restrict__ chist, float* __restrict__ out)
{
    __shared__ float wsum[4];
    const int tid  = threadIdx.x;
    const int lane = tid & 63;          // lane == bin
    const int w    = tid >> 6;          // wave id 0..3, handles 3 channels
    float acc = 0.0f;
    for (int c = w * 3; c < w * 3 + 3; ++c) {
        float cp = chist[c * BINS + lane];
        float ct = chist[(NCH + c) * BINS + lane];
        #pragma unroll
        for (int off = 1; off < 64; off <<= 1) {
            float a = __shfl_up(cp, off, 64);
            float b = __shfl_up(ct, off, 64);
            if (lane >= off) { cp += a; ct += b; }
        }
        float sp = __shfl(cp, 63, 64);
        float st = __shfl(ct, 63, 64);
        float diff = fabsf(cp / (sp + 1e-8f) - ct / (st + 1e-8f));
        #pragma unroll
        for (int off = 32; off; off >>= 1)
            diff += __shfl_xor(diff, off, 64);
        acc += diff;
    }
    if (lane == 0) wsum[w] = acc;
    __syncthreads();
    if (tid == 0)
        out[0] = (wsum[0] + wsum[1] + wsum[2] + wsum[3]) / (float)(NCH * BINS);
}

extern "C" void kernel_launch(void* const* d_in, const int* in_sizes, int n_in,
                              void* d_out, int out_size, void* d_ws, size_t ws_size,
                              hipStream_t stream)
{
    const float* pred   = (const float*)d_in[0];
    const float* target = (const float*)d_in[1];
    float* chist = (float*)d_ws;   // 2*12*64 = 1536 floats

    hipMemsetAsync(chist, 0, 2 * NCH * BINS * sizeof(float), stream);
    hist_kernel<<<dim3(CHUNKS, NCH), THREADS, 0, stream>>>(pred, target, chist);
    finalize_kernel<<<1, 256, 0, stream>>>(chist, (float*)d_out);
}

// Round 10
// 28.766 us; speedup vs baseline: 1.7808x; 1.7808x over previous
//
#include <hip/hip_runtime.h>
#include <hip/hip_fp16.h>
#include <stdint.h>

#define BINS    64
#define NSLOT   9                 // float4 slots per column: bins -4..67, fp16-packed
#define THREADS 128
#define CHUNKS  64                // blocks per channel-image
#define NPIX    (512*512)
#define PPB     (NPIX / CHUNKS)   // 4096 pixels per block
#define ITERS   (PPB / 4 / THREADS)   // 8
#define NCH     12                // 4*3 channel-images per input

__device__ __forceinline__ uint32_t h2add(uint32_t u, uint32_t w) {
    __half2 a = *(__half2*)&u, b = *(__half2*)&w;
    a = __hadd2(a, b);
    return *(uint32_t*)&a;
}

__global__ __launch_bounds__(THREADS) void hist_kernel(
    const float* __restrict__ pred, const float* __restrict__ target,
    float* __restrict__ part /* [2][NCH][CHUNKS][BINS] */)
{
    // TRANSPOSED: slot s (0..8) of column c lives at lh4[s*THREADS + c].
    // Main-loop bank-quad = tid mod 8 -> deterministic minimal conflicts.
    __shared__ __align__(16) float4 lh4[NSLOT * THREADS];   // 18432 B
    __shared__ float red[THREADS];                           // 512 B
    const int tid = threadIdx.x;

    #pragma unroll
    for (int s = 0; s < NSLOT; ++s)
        lh4[s * THREADS + tid] = make_float4(0.f, 0.f, 0.f, 0.f);
    __syncthreads();

    const int chunk = blockIdx.x;
    const int ch    = blockIdx.y;
    const int z     = blockIdx.z;
    const float* src = (z == 0 ? pred : target)
                     + (size_t)ch * NPIX + (size_t)chunk * PPB;
    const float4* src4 = (const float4*)src;

    // C_m = exp(-m*m/2)
    const float C1  = 0.60653065971f;
    const float C2  = 0.13533528324f;
    const float C3  = 1.11089965382e-2f;
    const float C4  = 3.35462627903e-4f;
    const float C5  = 3.72665317208e-6f;
    const float C6  = 1.52299797447e-8f;
    const float C7  = 2.28973484586e-11f;
    const float C8  = 1.26641655491e-14f;
    const float C9  = 2.57675710892e-18f;
    const float C10 = 1.92874984796e-22f;
    const float C11 = 5.31109225435e-27f;

    float4 v = src4[tid];
    #pragma unroll
    for (int k = 0; k < ITERS; ++k) {
        float4 vn = (k + 1 < ITERS) ? src4[(size_t)(k + 1) * THREADS + tid]
                                    : make_float4(0.f, 0.f, 0.f, 0.f);
        float xv[4] = {v.x, v.y, v.z, v.w};
        #pragma unroll
        for (int e = 0; e < 4; ++e) {
            float xs = xv[e] * 64.0f;            // [0, 64)
            float fo = floorf(xs * 0.125f);      // octet O: 0..7
            int   O  = (int)fo;
            float d0 = xs - 8.0f * fo - 0.5f;    // [-0.5, 7.5)
            // window bins 8O-4 .. 8O+11 (offset m=-4..11), t = d0-m
            // w_m = t0 * g^m * C_m ; e_m = t0*g^m chained (no over/underflow)
            float t0 = __expf(-0.5f * d0 * d0);
            float g  = __expf(d0);
            float gi = __expf(-d0);
            float e1 = t0*g,  e2 = e1*g,  e3 = e2*g,  e4 = e3*g;
            float e5 = e4*g,  e6 = e5*g,  e7 = e6*g,  e8 = e7*g;
            float e9 = e8*g,  e10= e9*g,  e11= e10*g;
            float f1 = t0*gi, f2 = f1*gi, f3 = f2*gi, f4 = f3*gi;
            // pack 16 weights into 8 half2 dwords (low half = even bin)
            uint32_t p0, p1, p2, p3, p4, p5, p6, p7;
            {
                __half2 q0 = __floats2half2_rn(f4*C4, f3*C3);   // m=-4,-3
                __half2 q1 = __floats2half2_rn(f2*C2, f1*C1);   // m=-2,-1
                __half2 q2 = __floats2half2_rn(t0,     e1*C1);  // m= 0, 1
                __half2 q3 = __floats2half2_rn(e2*C2,  e3*C3);  // m= 2, 3
                __half2 q4 = __floats2half2_rn(e4*C4,  e5*C5);  // m= 4, 5
                __half2 q5 = __floats2half2_rn(e6*C6,  e7*C7);  // m= 6, 7
                __half2 q6 = __floats2half2_rn(e8*C8,  e9*C9);  // m= 8, 9
                __half2 q7 = __floats2half2_rn(e10*C10, e11*C11); // m=10,11
                p0 = *(uint32_t*)&q0; p1 = *(uint32_t*)&q1;
                p2 = *(uint32_t*)&q2; p3 = *(uint32_t*)&q3;
                p4 = *(uint32_t*)&q4; p5 = *(uint32_t*)&q5;
                p6 = *(uint32_t*)&q6; p7 = *(uint32_t*)&q7;
            }
            // slots O (m=-4..3) and O+1 (m=4..11), transposed addresses
            float4* sA = &lh4[(O    ) * THREADS + tid];
            float4* sB = &lh4[(O + 1) * THREADS + tid];
            float4 a = *sA, b = *sB;
            uint32_t* au = (uint32_t*)&a;
            uint32_t* bu = (uint32_t*)&b;
            au[0] = h2add(au[0], p0); au[1] = h2add(au[1], p1);
            au[2] = h2add(au[2], p2); au[3] = h2add(au[3], p3);
            bu[0] = h2add(bu[0], p4); bu[1] = h2add(bu[1], p5);
            bu[2] = h2add(bu[2], p6); bu[3] = h2add(bu[3], p7);
            *sA = a; *sB = b;
        }
        v = vn;
    }
    __syncthreads();

    // fold: bin b -> slot s4, dword dw, half (b&1); stagger c by s4 so that
    // bank = (4*(i+s4)+dw) mod 32 is spread (collisions only on half-pairs,
    // which are same-address broadcasts).
    const int bin = tid & 63;
    const int h   = tid >> 6;
    const int j   = bin >> 1;
    const int s   = j + 2;
    const int s4  = s >> 2;
    const int dw  = s & 3;
    const uint32_t* lhu = (const uint32_t*)lh4;
    float acc = 0.0f;
    #pragma unroll 8
    for (int i = 0; i < 64; ++i) {
        int c = h * 64 + ((i + s4) & 63);
        uint32_t u = lhu[4 * (s4 * THREADS + c) + dw];
        __half2 hv = *(__half2*)&u;
        acc += (bin & 1) ? __high2float(hv) : __low2float(hv);
    }
    red[tid] = acc;
    __syncthreads();

    if (tid < 64) {
        float tot = red[tid] + red[tid + 64];
        part[(((size_t)z * NCH + ch) * CHUNKS + chunk) * BINS + tid] = tot;
    }
}

// Fold chunk partials: 24 blocks (one per channel-image), 64 threads (bin).
__global__ __launch_bounds__(64) void reduce_kernel(
    const float* __restrict__ part, float* __restrict__ chist /* [24][BINS] */)
{
    const int ci  = blockIdx.x;
    const int bin = threadIdx.x;
    float s = 0.0f;
    #pragma unroll 16
    for (int i = 0; i < CHUNKS; ++i)
        s += part[((size_t)ci * CHUNKS + i) * BINS + bin];
    chist[ci * BINS + bin] = s;
}

__global__ __launch_bounds__(256) void finalize_kernel(
    const float* __restrict__ chist, float* __restrict__ out)
{
    __shared__ float wsum[4];
    const int tid  = threadIdx.x;
    const int lane = tid & 63;          // lane == bin
    const int w    = tid >> 6;          // wave id 0..3, handles 3 channels
    float acc = 0.0f;
    for (int c = w * 3; c < w * 3 + 3; ++c) {
        float cp = chist[c * BINS + lane];
        float ct = chist[(NCH + c) * BINS + lane];
        #pragma unroll
        for (int off = 1; off < 64; off <<= 1) {
            float a = __shfl_up(cp, off, 64);
            float b = __shfl_up(ct, off, 64);
            if (lane >= off) { cp += a; ct += b; }
        }
        float sp = __shfl(cp, 63, 64);
        float st = __shfl(ct, 63, 64);
        float diff = fabsf(cp / (sp + 1e-8f) - ct / (st + 1e-8f));
        #pragma unroll
        for (int off = 32; off; off >>= 1)
            diff += __shfl_xor(diff, off, 64);
        acc += diff;
    }
    if (lane == 0) wsum[w] = acc;
    __syncthreads();
    if (tid == 0)
        out[0] = (wsum[0] + wsum[1] + wsum[2] + wsum[3]) / (float)(NCH * BINS);
}

extern "C" void kernel_launch(void* const* d_in, const int* in_sizes, int n_in,
                              void* d_out, int out_size, void* d_ws, size_t ws_size,
                              hipStream_t stream)
{
    const float* pred   = (const float*)d_in[0];
    const float* target = (const float*)d_in[1];
    float* part  = (float*)d_ws;                   // 2*12*64*64 floats
    float* chist = part + 2 * NCH * CHUNKS * BINS; // 24*64 floats

    hist_kernel<<<dim3(CHUNKS, NCH, 2), THREADS, 0, stream>>>(pred, target, part);
    reduce_kernel<<<2 * NCH, 64, 0, stream>>>(part, chist);
    finalize_kernel<<<1, 256, 0, stream>>>(chist, (float*)d_out);
}

// Round 11
// 26.380 us; speedup vs baseline: 1.9418x; 1.0904x over previous
//
#include <hip/hip_runtime.h>
#include <stdint.h>

#define BINS    64
#define SBINS   256               // sub-bins: 4 per bin (h = 1/4 bin)
#define CSTR    65                // dwords per u8-count column (256B + 4B pad); gcd(65,32)=1
#define THREADS 128
#define CHUNKS  64                // blocks per channel-image
#define NPIX    (512*512)
#define PPB     (NPIX / CHUNKS)   // 4096 pixels per block -> 32 px/thread (max count 32 < 255)
#define ITERS   (PPB / 4 / THREADS)   // 8
#define NCH     12                // 4*3 channel-images per input

__global__ __launch_bounds__(THREADS) void hist_kernel(
    const float* __restrict__ pred, const float* __restrict__ target,
    uint32_t* __restrict__ part /* [2][NCH][CHUNKS][SBINS] */)
{
    __shared__ uint32_t lh[THREADS * CSTR];   // 33280 B
    const int tid = threadIdx.x;

    uint32_t* col = &lh[tid * CSTR];
    #pragma unroll
    for (int i = 0; i < CSTR; ++i) col[i] = 0u;
    __syncthreads();

    const int chunk = blockIdx.x;
    const int ch    = blockIdx.y;
    const int z     = blockIdx.z;
    const float* src = (z == 0 ? pred : target)
                     + (size_t)ch * NPIX + (size_t)chunk * PPB;
    const float4* src4 = (const float4*)src;

    float4 v = src4[tid];
    #pragma unroll
    for (int k = 0; k < ITERS; ++k) {
        float4 vn = (k + 1 < ITERS) ? src4[(size_t)(k + 1) * THREADS + tid]
                                    : make_float4(0.f, 0.f, 0.f, 0.f);
        float xv[4] = {v.x, v.y, v.z, v.w};
        #pragma unroll
        for (int e = 0; e < 4; ++e) {
            int kq = (int)(xv[e] * 256.0f);      // sub-bin 0..255
            uint32_t dw = (uint32_t)kq >> 2;
            uint32_t sh = ((uint32_t)kq & 3u) << 3;
            col[dw] += (1u << sh);               // private column: no atomics
        }
        v = vn;
    }
    __syncthreads();

    // per-sub-bin totals across the 128 columns; thread t handles s=t, s=t+128
    const int s0 = tid, s1 = tid + THREADS;
    const int d0 = s0 >> 2, h0 = (s0 & 3) << 3;
    const int d1 = s1 >> 2, h1 = (s1 & 3) << 3;
    uint32_t a0 = 0u, a1 = 0u;
    #pragma unroll 8
    for (int c = 0; c < THREADS; ++c) {
        a0 += (lh[c * CSTR + d0] >> h0) & 0xffu;
        a1 += (lh[c * CSTR + d1] >> h1) & 0xffu;
    }
    uint32_t* pp = part + (((size_t)z * NCH + ch) * CHUNKS + chunk) * SBINS;
    pp[s0] = a0;
    pp[s1] = a1;
}

// One block per channel-image: fold chunk partials, then 36-tap Gaussian conv.
__global__ __launch_bounds__(SBINS) void reduce_conv_kernel(
    const uint32_t* __restrict__ part, float* __restrict__ chist /* [24][BINS] */)
{
    __shared__ float cnt[SBINS];
    const int ci = blockIdx.x;
    const int s  = threadIdx.x;
    uint32_t tot = 0u;
    #pragma unroll 8
    for (int i = 0; i < CHUNKS; ++i)
        tot += part[((size_t)ci * CHUNKS + i) * SBINS + s];
    cnt[s] = (float)tot;
    __syncthreads();

    if (s < BINS) {
        // hist_b = sum_u K(u) * cnt[4b+u], K(u) = exp(-((u-1.5)/4)^2 / 2)
        float h = 0.0f;
        #pragma unroll
        for (int u = -16; u <= 19; ++u) {
            int idx = 4 * s + u;
            float t = (u - 1.5f) * 0.25f;
            float K = __expf(-0.5f * t * t);
            if (idx >= 0 && idx < SBINS) h += K * cnt[idx];
        }
        chist[ci * BINS + s] = h;
    }
}

__global__ __launch_bounds__(256) void finalize_kernel(
    const float* __restrict__ chist, float* __restrict__ out)
{
    __shared__ float wsum[4];
    const int tid  = threadIdx.x;
    const int lane = tid & 63;          // lane == bin
    const int w    = tid >> 6;          // wave id 0..3, handles 3 channels
    float acc = 0.0f;
    for (int c = w * 3; c < w * 3 + 3; ++c) {
        float cp = chist[c * BINS + lane];
        float ct = chist[(NCH + c) * BINS + lane];
        #pragma unroll
        for (int off = 1; off < 64; off <<= 1) {
            float a = __shfl_up(cp, off, 64);
            float b = __shfl_up(ct, off, 64);
            if (lane >= off) { cp += a; ct += b; }
        }
        float sp = __shfl(cp, 63, 64);
        float st = __shfl(ct, 63, 64);
        float diff = fabsf(cp / (sp + 1e-8f) - ct / (st + 1e-8f));
        #pragma unroll
        for (int off = 32; off; off >>= 1)
            diff += __shfl_xor(diff, off, 64);
        acc += diff;
    }
    if (lane == 0) wsum[w] = acc;
    __syncthreads();
    if (tid == 0)
        out[0] = (wsum[0] + wsum[1] + wsum[2] + wsum[3]) / (float)(NCH * BINS);
}

extern "C" void kernel_launch(void* const* d_in, const int* in_sizes, int n_in,
                              void* d_out, int out_size, void* d_ws, size_t ws_size,
                              hipStream_t stream)
{
    const float* pred   = (const float*)d_in[0];
    const float* target = (const float*)d_in[1];
    uint32_t* part  = (uint32_t*)d_ws;                    // 24*64*256 u32 = 1.57 MB
    float*    chist = (float*)(part + 2 * NCH * CHUNKS * SBINS); // 24*64 f32

    hist_kernel<<<dim3(CHUNKS, NCH, 2), THREADS, 0, stream>>>(pred, target, part);
    reduce_conv_kernel<<<2 * NCH, SBINS, 0, stream>>>(part, chist);
    finalize_kernel<<<1, 256, 0, stream>>>(chist, (float*)d_out);
}